// Round 1
// baseline (146.959 us; speedup 1.0000x reference)
//
#include <hip/hip_runtime.h>
#include <hip/hip_bf16.h>

typedef __attribute__((ext_vector_type(8))) short short8;
typedef __attribute__((ext_vector_type(4))) float f32x4;

#define NROWS 8192
#define DCOLS 256
#define MARGIN 0.5f

// --- Kernel 1: L2-normalize rows fp32 -> bf16, one wave per row; also zero acc ---
__global__ __launch_bounds__(256) void norm_kernel(const float* __restrict__ x,
                                                   unsigned short* __restrict__ e,
                                                   float* __restrict__ acc) {
    if (blockIdx.x == 0 && threadIdx.x == 0) acc[0] = 0.0f;
    const int wave = threadIdx.x >> 6;
    const int lane = threadIdx.x & 63;
    const int row = blockIdx.x * 4 + wave;

    const float4 v = *reinterpret_cast<const float4*>(&x[row * DCOLS + lane * 4]);
    float ss = v.x * v.x + v.y * v.y + v.z * v.z + v.w * v.w;
#pragma unroll
    for (int off = 32; off >= 1; off >>= 1) ss += __shfl_down(ss, off);
    ss = __shfl(ss, 0);
    const float inv = 1.0f / fmaxf(sqrtf(ss), 1e-12f);

    __hip_bfloat16 h0 = __float2bfloat16(v.x * inv);
    __hip_bfloat16 h1 = __float2bfloat16(v.y * inv);
    __hip_bfloat16 h2 = __float2bfloat16(v.z * inv);
    __hip_bfloat16 h3 = __float2bfloat16(v.w * inv);
    ushort4 o;
    o.x = *reinterpret_cast<unsigned short*>(&h0);
    o.y = *reinterpret_cast<unsigned short*>(&h1);
    o.z = *reinterpret_cast<unsigned short*>(&h2);
    o.w = *reinterpret_cast<unsigned short*>(&h3);
    *reinterpret_cast<ushort4*>(&e[row * DCOLS + lane * 4]) = o;
}

// --- Kernel 2: 128x128 sim tiles (upper triangle only), fused relu+mask+sum ---
// Block = 256 threads = 4 waves in 2x2; each wave computes a 64x64 sub-tile
// via 4x4 grid of 16x16x32 bf16 MFMAs over K=256.
__global__ __launch_bounds__(256) void tile_kernel(const unsigned short* __restrict__ e,
                                                   float* __restrict__ acc) {
    const int bj = blockIdx.x;   // col tile
    const int bi = blockIdx.y;   // row tile
    if (bi > bj) return;         // lower-triangle tiles contribute nothing

    const int lane = threadIdx.x & 63;
    const int w    = threadIdx.x >> 6;   // 0..3
    const int wr   = w >> 1;             // wave row 0..1
    const int wc   = w & 1;              // wave col 0..1
    const int lr   = lane & 15;          // fragment row/col index
    const int hk   = lane >> 4;          // k-group 0..3

    const int arow0 = bi * 128 + wr * 64;
    const int brow0 = bj * 128 + wc * 64;

    f32x4 c[4][4];
#pragma unroll
    for (int m = 0; m < 4; ++m)
#pragma unroll
        for (int n = 0; n < 4; ++n)
            c[m][n] = (f32x4){0.f, 0.f, 0.f, 0.f};

#pragma unroll
    for (int kb = 0; kb < DCOLS; kb += 32) {
        short8 a[4], b[4];
#pragma unroll
        for (int m = 0; m < 4; ++m)
            a[m] = *reinterpret_cast<const short8*>(
                &e[(arow0 + m * 16 + lr) * DCOLS + kb + hk * 8]);
#pragma unroll
        for (int n = 0; n < 4; ++n)
            b[n] = *reinterpret_cast<const short8*>(
                &e[(brow0 + n * 16 + lr) * DCOLS + kb + hk * 8]);
#pragma unroll
        for (int m = 0; m < 4; ++m)
#pragma unroll
            for (int n = 0; n < 4; ++n)
                c[m][n] = __builtin_amdgcn_mfma_f32_16x16x32_bf16(a[m], b[n], c[m][n], 0, 0, 0);
    }

    // Epilogue: relu(sim - margin) with strict upper-triangle mask, lane-local sum.
    // C/D layout (m89-verified): col = lane&15, row = (lane>>4)*4 + reg.
    float local = 0.0f;
#pragma unroll
    for (int m = 0; m < 4; ++m) {
#pragma unroll
        for (int n = 0; n < 4; ++n) {
#pragma unroll
            for (int r = 0; r < 4; ++r) {
                const int gi = arow0 + m * 16 + hk * 4 + r;
                const int gj = brow0 + n * 16 + lr;
                const float v = c[m][n][r] - MARGIN;
                local += (gi < gj) ? fmaxf(v, 0.0f) : 0.0f;
            }
        }
    }
#pragma unroll
    for (int off = 32; off >= 1; off >>= 1) local += __shfl_down(local, off);
    if (lane == 0) atomicAdd(acc, local);
}

// --- Kernel 3: finalize ---
__global__ void fin_kernel(const float* __restrict__ acc, float* __restrict__ out) {
    out[0] = acc[0] / 33550336.0f;   // n*(n-1)/2 for n=8192
}

extern "C" void kernel_launch(void* const* d_in, const int* in_sizes, int n_in,
                              void* d_out, int out_size, void* d_ws, size_t ws_size,
                              hipStream_t stream) {
    const float* x = (const float*)d_in[0];
    float* out = (float*)d_out;
    unsigned short* e = (unsigned short*)d_ws;
    float* acc = (float*)((char*)d_ws + (size_t)NROWS * DCOLS * 2);

    norm_kernel<<<NROWS / 4, 256, 0, stream>>>(x, e, acc);
    tile_kernel<<<dim3(64, 64), 256, 0, stream>>>(e, acc);
    fin_kernel<<<1, 1, 0, stream>>>(acc, out);
}

// Round 3
// 46.621 us; speedup vs baseline: 3.1522x; 3.1522x over previous
//
#include <hip/hip_runtime.h>
#include <hip/hip_bf16.h>

typedef __attribute__((ext_vector_type(8))) short short8;
typedef __attribute__((ext_vector_type(4))) float f32x4;

#define NROWS 8192
#define DCOLS 256
#define MARGIN 0.5f
#define BM 128
#define BK 64

// --- Kernel 1: L2-normalize rows fp32 -> bf16, one wave per row; also zero acc ---
__global__ __launch_bounds__(256) void norm_kernel(const float* __restrict__ x,
                                                   unsigned short* __restrict__ e,
                                                   float* __restrict__ acc) {
    if (blockIdx.x == 0 && threadIdx.x == 0) acc[0] = 0.0f;
    const int wave = threadIdx.x >> 6;
    const int lane = threadIdx.x & 63;
    const int row = blockIdx.x * 4 + wave;

    const float4 v = *reinterpret_cast<const float4*>(&x[row * DCOLS + lane * 4]);
    float ss = v.x * v.x + v.y * v.y + v.z * v.z + v.w * v.w;
#pragma unroll
    for (int off = 32; off >= 1; off >>= 1) ss += __shfl_down(ss, off);
    ss = __shfl(ss, 0);
    const float inv = 1.0f / fmaxf(sqrtf(ss), 1e-12f);

    __hip_bfloat16 h0 = __float2bfloat16(v.x * inv);
    __hip_bfloat16 h1 = __float2bfloat16(v.y * inv);
    __hip_bfloat16 h2 = __float2bfloat16(v.z * inv);
    __hip_bfloat16 h3 = __float2bfloat16(v.w * inv);
    ushort4 o;
    o.x = *reinterpret_cast<unsigned short*>(&h0);
    o.y = *reinterpret_cast<unsigned short*>(&h1);
    o.z = *reinterpret_cast<unsigned short*>(&h2);
    o.w = *reinterpret_cast<unsigned short*>(&h3);
    *reinterpret_cast<ushort4*>(&e[row * DCOLS + lane * 4]) = o;
}

// --- Kernel 2: 128x128 sim tiles (upper triangle only), LDS-staged MFMA GEMM,
// fused relu+mask+sum epilogue. 4 waves (2x2), each wave 64x64 via 4x4 MFMAs.
// LDS: A/B panels [128][64] bf16 (16KB each), single-buffered, BK=64, 4 K-steps.
// XOR swizzle (slot ^= row&7): linear LDS dest for global_load_lds, inverse-
// swizzled global source column, swizzled ds_read address (rule #21).
__global__ __launch_bounds__(256, 4) void tile_kernel(const unsigned short* __restrict__ e,
                                                      float* __restrict__ acc) {
    const int bj = blockIdx.x;   // col tile
    const int bi = blockIdx.y;   // row tile
    if (bi > bj) return;         // lower-triangle tiles contribute nothing

    __shared__ unsigned short As[BM * BK];   // 16 KB
    __shared__ unsigned short Bs[BM * BK];   // 16 KB
    __shared__ float red[4];

    const int t = threadIdx.x;
    const int l = t & 63;
    const int w = t >> 6;        // 0..3
    const int wr = w >> 1;       // wave row 0..1
    const int wc = w & 1;        // wave col 0..1
    const int lr = l & 15;       // fragment row index
    const int hk = l >> 4;       // k-group 0..3

    const unsigned short* eA = e + (size_t)bi * 128 * DCOLS;
    const unsigned short* eB = e + (size_t)bj * 128 * DCOLS;

    f32x4 c[4][4];
#pragma unroll
    for (int m = 0; m < 4; ++m)
#pragma unroll
        for (int n = 0; n < 4; ++n)
            c[m][n] = (f32x4){0.f, 0.f, 0.f, 0.f};

    for (int ks = 0; ks < 4; ++ks) {
        const int k0 = ks * BK;
        // --- stage: 16KB A + 16KB B via global_load_lds width 16 ---
        // chunk = i*256 + w*64 + l -> LDS byte (chunk*16), linear in lane.
        // logical: row = chunk>>3, slot = chunk&7 holds col-group slot^(row&7).
#pragma unroll
        for (int i = 0; i < 4; ++i) {
            const int chunk = i * 256 + w * 64 + l;
            const int row   = chunk >> 3;
            const int cg    = (chunk & 7) ^ (row & 7);
            const int goff  = row * DCOLS + k0 + cg * 8;
            __builtin_amdgcn_global_load_lds(
                (const __attribute__((address_space(1))) void*)(eA + goff),
                (__attribute__((address_space(3))) void*)((char*)As + i * 4096 + w * 1024),
                16, 0, 0);
            __builtin_amdgcn_global_load_lds(
                (const __attribute__((address_space(1))) void*)(eB + goff),
                (__attribute__((address_space(3))) void*)((char*)Bs + i * 4096 + w * 1024),
                16, 0, 0);
        }
        __syncthreads();   // drains vmcnt before barrier -> staged data visible

        // --- compute: 2 kk substeps of K=32, 16 MFMAs each ---
#pragma unroll
        for (int kk = 0; kk < 2; ++kk) {
            const int cg = kk * 4 + hk;
            short8 a[4], b[4];
#pragma unroll
            for (int m = 0; m < 4; ++m) {
                const int r = wr * 64 + m * 16 + lr;
                a[m] = *reinterpret_cast<const short8*>(
                    (const char*)As + r * 128 + ((cg ^ (r & 7)) << 4));
            }
#pragma unroll
            for (int n = 0; n < 4; ++n) {
                const int r = wc * 64 + n * 16 + lr;
                b[n] = *reinterpret_cast<const short8*>(
                    (const char*)Bs + r * 128 + ((cg ^ (r & 7)) << 4));
            }
#pragma unroll
            for (int m = 0; m < 4; ++m)
#pragma unroll
                for (int n = 0; n < 4; ++n)
                    c[m][n] = __builtin_amdgcn_mfma_f32_16x16x32_bf16(a[m], b[n], c[m][n], 0, 0, 0);
        }
        __syncthreads();   // protect LDS from next stage
    }

    // --- epilogue: relu(sim - margin), strict upper-triangle mask, reduce ---
    // C/D layout (m89-verified): col = lane&15, row = (lane>>4)*4 + reg.
    const int arow0 = bi * 128 + wr * 64;
    const int brow0 = bj * 128 + wc * 64;
    float local = 0.0f;
#pragma unroll
    for (int m = 0; m < 4; ++m) {
#pragma unroll
        for (int n = 0; n < 4; ++n) {
#pragma unroll
            for (int r = 0; r < 4; ++r) {
                const int gi = arow0 + m * 16 + hk * 4 + r;
                const int gj = brow0 + n * 16 + lr;
                const float v = c[m][n][r] - MARGIN;
                local += (gi < gj) ? fmaxf(v, 0.0f) : 0.0f;
            }
        }
    }
#pragma unroll
    for (int off = 32; off >= 1; off >>= 1) local += __shfl_down(local, off);
    if (l == 0) red[w] = local;
    __syncthreads();
    if (t == 0) atomicAdd(acc, red[0] + red[1] + red[2] + red[3]);
}

// --- Kernel 3: finalize ---
__global__ void fin_kernel(const float* __restrict__ acc, float* __restrict__ out) {
    out[0] = acc[0] / 33550336.0f;   // n*(n-1)/2 for n=8192
}

extern "C" void kernel_launch(void* const* d_in, const int* in_sizes, int n_in,
                              void* d_out, int out_size, void* d_ws, size_t ws_size,
                              hipStream_t stream) {
    const float* x = (const float*)d_in[0];
    float* out = (float*)d_out;
    unsigned short* e = (unsigned short*)d_ws;
    float* acc = (float*)((char*)d_ws + (size_t)NROWS * DCOLS * 2);

    norm_kernel<<<NROWS / 4, 256, 0, stream>>>(x, e, acc);
    tile_kernel<<<dim3(64, 64), 256, 0, stream>>>(e, acc);
    fin_kernel<<<1, 1, 0, stream>>>(acc, out);
}